// Round 5
// baseline (5494.665 us; speedup 1.0000x reference)
//
#include <hip/hip_runtime.h>
#include <cmath>

#define D 64

__device__ __forceinline__ float wave_reduce_sum(float v) {
  #pragma unroll
  for (int off = 32; off > 0; off >>= 1) v += __shfl_xor(v, off, 64);
  return v;
}
__device__ __forceinline__ float wave_reduce_max(float v) {
  #pragma unroll
  for (int off = 32; off > 0; off >>= 1) v = fmaxf(v, __shfl_xor(v, off, 64));
  return v;
}
__device__ __forceinline__ int wave_reduce_sum_i(int v) {
  #pragma unroll
  for (int off = 32; off > 0; off >>= 1) v += __shfl_xor(v, off, 64);
  return v;
}

// ---- row accumulate: 4 edge-groups x 16 lanes, lane owns dims 4c..4c+3 (float4) ----
__device__ __forceinline__ void row_accum4(const int2* __restrict__ edata, int lo, int hi,
                                           const float* __restrict__ ftab, int g, int c4,
                                           float4& acc) {
  for (int base = lo; base < hi; base += 8) {
    int j0 = base + g, j1 = base + 4 + g;
    int2 e0 = (j0 < hi) ? edata[j0] : make_int2(0, 0);
    int2 e1 = (j1 < hi) ? edata[j1] : make_int2(0, 0);
    float4 f0 = *(const float4*)(ftab + (size_t)e0.x * D + c4);
    float4 f1 = *(const float4*)(ftab + (size_t)e1.x * D + c4);
    float v0 = __int_as_float(e0.y), v1 = __int_as_float(e1.y);
    acc.x = fmaf(v0, f0.x, acc.x); acc.y = fmaf(v0, f0.y, acc.y);
    acc.z = fmaf(v0, f0.z, acc.z); acc.w = fmaf(v0, f0.w, acc.w);
    acc.x = fmaf(v1, f1.x, acc.x); acc.y = fmaf(v1, f1.y, acc.y);
    acc.z = fmaf(v1, f1.z, acc.z); acc.w = fmaf(v1, f1.w, acc.w);
  }
}

__device__ __forceinline__ float4 cg_reduce4(float4 a) {
  a.x += __shfl_xor(a.x, 16, 64); a.x += __shfl_xor(a.x, 32, 64);
  a.y += __shfl_xor(a.y, 16, 64); a.y += __shfl_xor(a.y, 32, 64);
  a.z += __shfl_xor(a.z, 16, 64); a.z += __shfl_xor(a.z, 32, 64);
  a.w += __shfl_xor(a.w, 16, 64); a.w += __shfl_xor(a.w, 32, 64);
  return a;  // lanes 0..15 (and replicas) hold full row in float4s
}

// ---------------- CSR build ----------------

__global__ void mark_usel(const int* __restrict__ uid, int* __restrict__ usel, int B) {
  int b = blockIdx.x * blockDim.x + threadIdx.x;
  if (b < B) usel[uid[b]] = 1;
}

__global__ void hist_src(const int* __restrict__ src, int* __restrict__ deg, int n, int h,
                         const int* __restrict__ usel, int filt) {
  int e = blockIdx.x * blockDim.x + threadIdx.x;
  if (e >= n) return;
  int s = src[e];
  if (filt && e < h && usel[s] == 0) return;
  atomicAdd(&deg[s], 1);
}

// ---- coalesced 3-pass exclusive scan over deg[N] -> rowptr[N+1], cursor[N] ----
#define SCHUNK 2048

__global__ void scan_p1(const int* __restrict__ deg, int* __restrict__ bsum, int N) {
  int b = blockIdx.x, t = threadIdx.x;
  int lo = b * SCHUNK;
  int s = 0;
  #pragma unroll
  for (int k = 0; k < 8; ++k) { int i = lo + k * 256 + t; if (i < N) s += deg[i]; }
  s = wave_reduce_sum_i(s);
  __shared__ int ws[4];
  if ((t & 63) == 0) ws[t >> 6] = s;
  __syncthreads();
  if (t == 0) bsum[b] = ws[0] + ws[1] + ws[2] + ws[3];
}

__global__ __launch_bounds__(1024) void scan_p2(int* __restrict__ bsum, int nb,
                                                int* __restrict__ rowptr, int N) {
  __shared__ int arr[1024];
  int t = threadIdx.x;
  int v = (t < nb) ? bsum[t] : 0;
  arr[t] = v; __syncthreads();
  for (int off = 1; off < 1024; off <<= 1) {
    int x = (t >= off) ? arr[t - off] : 0;
    __syncthreads();
    arr[t] += x;
    __syncthreads();
  }
  if (t < nb) bsum[t] = t ? arr[t - 1] : 0;
  if (t == 0) rowptr[N] = arr[nb - 1];
}

__global__ void scan_p3(const int* __restrict__ deg, const int* __restrict__ bsum,
                        int* __restrict__ rowptr, int* __restrict__ cursor, int N) {
  int b = blockIdx.x, t = threadIdx.x;
  int lane = t & 63, wid = t >> 6;
  int base = b * SCHUNK + t * 8;
  int x[8], excl[8], s = 0;
  #pragma unroll
  for (int k = 0; k < 8; ++k) x[k] = (base + k < N) ? deg[base + k] : 0;
  #pragma unroll
  for (int k = 0; k < 8; ++k) { excl[k] = s; s += x[k]; }
  int incl = s;
  #pragma unroll
  for (int off = 1; off < 64; off <<= 1) {
    int y = __shfl_up(incl, off, 64);
    if (lane >= off) incl += y;
  }
  int wave_excl = incl - s;
  __shared__ int wsumS[4];
  if (lane == 63) wsumS[wid] = incl;
  __syncthreads();
  int wo = 0;
  for (int w = 0; w < wid; ++w) wo += wsumS[w];
  int off0 = bsum[b] + wo + wave_excl;
  #pragma unroll
  for (int k = 0; k < 8; ++k) {
    int i = base + k;
    if (i < N) { rowptr[i] = off0 + excl[k]; cursor[i] = off0 + excl[k]; }
  }
}

// ---- Pass A: compute exact CSR pos, append packed record at bucket frontier ----
// record: word0 = (pos & 8191) | (dst_local << 13), word1 = val bits
__global__ void scatter_bucketed(const int* __restrict__ src, const int* __restrict__ dst,
                                 const float* __restrict__ vals, int* __restrict__ cursor,
                                 int* __restrict__ bcur, uint2* __restrict__ brec,
                                 int n, int h, int NU,
                                 const int* __restrict__ usel, int filt) {
  int e = blockIdx.x * blockDim.x + threadIdx.x;
  if (e >= n) return;
  int s = src[e];
  if (filt && e < h && usel[s] == 0) return;
  int t = dst[e];
  if (e < h) t -= NU;  // first half: item-global -> local; second half: already user id
  int pos = atomicAdd(&cursor[s], 1);
  int bkt = pos >> 13;
  int slot = atomicAdd(&bcur[bkt], 1);
  brec[((size_t)bkt << 13) + slot] =
      make_uint2((unsigned)(pos & 8191) | ((unsigned)t << 13), __float_as_uint(vals[e]));
}

// ---- Pass B: per-bucket LDS permute, fully coalesced edata write ----
__global__ __launch_bounds__(256) void debucket(const uint2* __restrict__ brec,
                                                const int* __restrict__ rowptr,
                                                int2* __restrict__ edata, int N) {
  __shared__ int2 lds[8192];
  int b = blockIdx.x, t = threadIdx.x;
  int total = rowptr[N];
  int base = b << 13;
  int nb = total - base;
  if (nb <= 0) return;
  if (nb > 8192) nb = 8192;
  for (int k = t; k < nb; k += 256) {
    uint2 r = brec[(size_t)base + k];
    lds[r.x & 8191u] = make_int2((int)(r.x >> 13), (int)r.y);
  }
  __syncthreads();
  for (int k = t; k < nb; k += 256) edata[(size_t)base + k] = lds[k];
}

// ---------------- SpMM layer kernels ----------------

__global__ void spmm_l1(const int* __restrict__ rowptr, const int2* __restrict__ edata,
                        const float* __restrict__ userF, const float* __restrict__ itemF,
                        float* __restrict__ ul1, float* __restrict__ il1,
                        int row0, int nrows, int NU) {
  int r = row0 + blockIdx.x * 4 + (threadIdx.x >> 6);
  if (r >= row0 + nrows) return;
  int lane = threadIdx.x & 63, g = lane >> 4, c4 = (lane & 15) * 4;
  const float* ftab = (r < NU) ? itemF : userF;
  float4 a = make_float4(0.f, 0.f, 0.f, 0.f);
  row_accum4(edata, rowptr[r], rowptr[r + 1], ftab, g, c4, a);
  a = cg_reduce4(a);
  if (g == 0) {
    float* out = (r < NU) ? (ul1 + (size_t)r * D) : (il1 + (size_t)(r - NU) * D);
    *(float4*)(out + c4) = a;
  }
}

__global__ void spmm_l1_uid(const int* __restrict__ rowptr, const int2* __restrict__ edata,
                            const float* __restrict__ itemF, float* __restrict__ ul1,
                            const int* __restrict__ uid, int B) {
  int b = blockIdx.x * 4 + (threadIdx.x >> 6);
  if (b >= B) return;
  int lane = threadIdx.x & 63, g = lane >> 4, c4 = (lane & 15) * 4;
  int r = uid[b];
  float4 a = make_float4(0.f, 0.f, 0.f, 0.f);
  row_accum4(edata, rowptr[r], rowptr[r + 1], itemF, g, c4, a);
  a = cg_reduce4(a);
  if (g == 0) *(float4*)(ul1 + (size_t)r * D + c4) = a;  // dup uids: identical values
}

__global__ void final_item(const int* __restrict__ rowptr, const int2* __restrict__ edata,
                           const float* __restrict__ ul1, const float* __restrict__ il1,
                           const float* __restrict__ itemF, float* __restrict__ out,
                           int NU, int NI) {
  int i = blockIdx.x * 4 + (threadIdx.x >> 6);
  if (i >= NI) return;
  int lane = threadIdx.x & 63, g = lane >> 4, c4 = (lane & 15) * 4;
  int r = NU + i;
  float4 a = make_float4(0.f, 0.f, 0.f, 0.f);
  row_accum4(edata, rowptr[r], rowptr[r + 1], ul1, g, c4, a);
  a = cg_reduce4(a);
  if (g == 0) {
    size_t o = (size_t)i * D + c4;
    float4 itf = *(const float4*)(itemF + o);
    float4 il  = *(const float4*)(il1 + o);
    float4 res;
    res.x = (itf.x + il.x + a.x) * (1.f / 3.f);
    res.y = (itf.y + il.y + a.y) * (1.f / 3.f);
    res.z = (itf.z + il.z + a.z) * (1.f / 3.f);
    res.w = (itf.w + il.w + a.w) * (1.f / 3.f);
    *(float4*)(out + o) = res;
  }
}

__global__ void final_uid(const int* __restrict__ rowptr, const int2* __restrict__ edata,
                          const float* __restrict__ il1, const float* __restrict__ ul1,
                          const float* __restrict__ userF, const int* __restrict__ uid,
                          float* __restrict__ ug, int add, int B) {
  int b = blockIdx.x * 4 + (threadIdx.x >> 6);
  if (b >= B) return;
  int lane = threadIdx.x & 63, g = lane >> 4, c4 = (lane & 15) * 4;
  int u = uid[b];
  float4 a = make_float4(0.f, 0.f, 0.f, 0.f);
  row_accum4(edata, rowptr[u], rowptr[u + 1], il1, g, c4, a);
  a = cg_reduce4(a);
  if (g == 0) {
    size_t uo = (size_t)u * D + c4;
    float4 uf = *(const float4*)(userF + uo);
    float4 ul = *(const float4*)(ul1 + uo);
    float4 res;
    res.x = (uf.x + ul.x + a.x) * (1.f / 3.f);
    res.y = (uf.y + ul.y + a.y) * (1.f / 3.f);
    res.z = (uf.z + ul.z + a.z) * (1.f / 3.f);
    res.w = (uf.w + ul.w + a.w) * (1.f / 3.f);
    float4* dst = (float4*)(ug + (size_t)b * D + c4);
    if (add) {
      float4 old = *dst;
      res.x += old.x; res.y += old.y; res.z += old.z; res.w += old.w;
    }
    *dst = res;
  }
}

// ---------------- fused attention + MLP + output ----------------

__global__ __launch_bounds__(64) void attn_final(
    const float* __restrict__ e1, const float* __restrict__ pe,
    const int* __restrict__ seq, const int* __restrict__ mask,
    const float* __restrict__ wq_w, const float* __restrict__ wq_b,
    const float* __restrict__ wk_w, const float* __restrict__ wk_b,
    const float* __restrict__ wv_w, const float* __restrict__ wv_b,
    const float* __restrict__ mlp_w, const float* __restrict__ mlp_b,
    const float* __restrict__ ug, const float* __restrict__ c1,
    const int* __restrict__ cid, float* __restrict__ out, int T) {
  __shared__ float xs[64][D];
  __shared__ float wks[D * D];
  __shared__ float wvs[D * D];
  __shared__ float ps[D];
  __shared__ float ys[D];
  __shared__ float atts[D];
  int b = blockIdx.x, d = threadIdx.x;

  for (int i = d; i < D * D; i += 64) { wks[i] = wk_w[i]; wvs[i] = wv_w[i]; }
  for (int t = 0; t < T; ++t) {
    int sidx = seq[b * T + t];
    xs[t][d] = e1[(size_t)sidx * D + d] + pe[t * D + d];
  }
  __syncthreads();

  float qd = wq_b[d];
  #pragma unroll 4
  for (int j = 0; j < D; ++j) qd = fmaf(xs[T - 1][j], wq_w[j * D + d], qd);
  if (mask[b * T + (T - 1)] == 0) qd = -100000.0f;

  float my_score = -INFINITY;
  for (int t = 0; t < T; ++t) {
    float kd = wk_b[d];
    #pragma unroll 8
    for (int j = 0; j < D; ++j) kd = fmaf(xs[t][j], wks[j * D + d], kd);
    if (mask[b * T + t] == 0) kd = -100000.0f;
    float s = wave_reduce_sum(qd * kd) * 0.125f;
    if (d == t) my_score = s;
  }
  float m = wave_reduce_max(my_score);
  float p = (d < T) ? expf(my_score - m) : 0.f;
  float sum = wave_reduce_sum(p);
  ps[d] = p / sum;
  __syncthreads();

  float yj = 0.f;
  for (int t = 0; t < T; ++t) yj = fmaf(ps[t], xs[t][d], yj);
  ys[d] = yj;
  __syncthreads();
  float ad = wv_b[d];
  #pragma unroll 8
  for (int j = 0; j < D; ++j) ad = fmaf(ys[j], wvs[j * D + d], ad);
  atts[d] = ad;
  __syncthreads();

  float h = mlp_b[d];
  #pragma unroll 4
  for (int j = 0; j < D; ++j) h = fmaf(ug[(size_t)b * D + j], mlp_w[j * D + d], h);
  #pragma unroll 4
  for (int j = 0; j < D; ++j) h = fmaf(atts[j], mlp_w[(D + j) * D + d], h);
  h = fmaxf(h, 0.f);

  #pragma unroll
  for (int c = 0; c < 2; ++c) {
    int cc = cid[b * 2 + c];
    float s = wave_reduce_sum(h * c1[(size_t)cc * D + d]);
    if (d == 0) out[b * 2 + c] = s;
  }
}

// ---------------- host ----------------

extern "C" void kernel_launch(void* const* d_in, const int* in_sizes, int n_in,
                              void* d_out, int out_size, void* d_ws, size_t ws_size,
                              hipStream_t stream) {
  const float* usersF   = (const float*)d_in[0];
  const float* coursesF = (const float*)d_in[1];
  const float* exF      = (const float*)d_in[2];
  const float* knF      = (const float*)d_in[3];
  const float* wq_w = (const float*)d_in[4];
  const float* wq_b = (const float*)d_in[5];
  const float* wk_w = (const float*)d_in[6];
  const float* wk_b = (const float*)d_in[7];
  const float* wv_w = (const float*)d_in[8];
  const float* wv_b = (const float*)d_in[9];
  const float* mlp_w = (const float*)d_in[10];
  const float* mlp_b = (const float*)d_in[11];
  const float* pe = (const float*)d_in[12];
  const float* uc_vals = (const float*)d_in[13];
  const float* ue_vals = (const float*)d_in[14];
  const float* uk_vals = (const float*)d_in[15];
  const int* uc_src = (const int*)d_in[16];
  const int* uc_dst = (const int*)d_in[17];
  const int* ue_src = (const int*)d_in[18];
  const int* ue_dst = (const int*)d_in[19];
  const int* uk_src = (const int*)d_in[20];
  const int* uk_dst = (const int*)d_in[21];
  const int* mask = (const int*)d_in[22];
  const int* seq  = (const int*)d_in[23];
  const int* uid  = (const int*)d_in[24];
  const int* cid  = (const int*)d_in[25];

  int NU = in_sizes[0] / D;
  int NC = in_sizes[1] / D;
  int NE = in_sizes[2] / D;
  int NK = in_sizes[3] / D;
  int B  = in_sizes[24];
  int T  = in_sizes[22] / B;
  int n2_uc = in_sizes[13], n2_ue = in_sizes[14], n2_uk = in_sizes[15];

  int NImax = NC > NE ? NC : NE; NImax = NImax > NK ? NImax : NK;
  int Nmax = NU + NImax;
  int n2max = n2_uc > n2_ue ? n2_uc : n2_ue; n2max = n2max > n2_uk ? n2max : n2_uk;
  int nbkmax = (n2max + 8191) >> 13;

  char* w = (char*)d_ws;
  auto alloc = [&](size_t bytes) { void* p = (void*)w; w += (bytes + 255) & ~(size_t)255; return p; };
  int2*  edata  = (int2*)alloc((size_t)n2max * 8);
  float* ul1    = (float*)alloc((size_t)NU * D * 4);   // also overlays brec during builds
  float* il1    = (float*)alloc((size_t)NImax * D * 4);
  float* e1     = (float*)alloc((size_t)NE * D * 4);
  float* c1     = (float*)alloc((size_t)NC * D * 4);
  float* ug     = (float*)alloc((size_t)B * D * 4);
  int*   rowptr = (int*)alloc((size_t)(Nmax + 1) * 4);
  int*   deg    = (int*)alloc((size_t)Nmax * 4);
  int*   cursor = (int*)alloc((size_t)Nmax * 4);
  int*   usel   = (int*)alloc((size_t)NU * 4);
  int*   bsum   = (int*)alloc((size_t)1024 * 4);
  int*   bcur   = (int*)alloc((size_t)(nbkmax + 1) * 4);
  uint2* brec   = (uint2*)ul1;  // overlay: dead outside [passA, passB]; ul1 rewritten after

  hipMemsetAsync(usel, 0, (size_t)NU * 4, stream);
  mark_usel<<<(B + 255) / 256, 256, 0, stream>>>(uid, usel, B);

  auto run_graph = [&](const int* src, const int* dst, const float* vals, int n2,
                       int NI, const float* itemF, int filt, float* itemOut, int add) {
    int N = NU + NI;
    int h = n2 / 2;
    unsigned eg = (unsigned)((n2 + 255) / 256);
    int nb = (N + SCHUNK - 1) / SCHUNK;
    int nbk = (n2 + 8191) >> 13;
    hipMemsetAsync(deg, 0, (size_t)N * 4, stream);
    hipMemsetAsync(bcur, 0, (size_t)nbk * 4, stream);
    hist_src<<<eg, 256, 0, stream>>>(src, deg, n2, h, usel, filt);
    scan_p1<<<(unsigned)nb, 256, 0, stream>>>(deg, bsum, N);
    scan_p2<<<1, 1024, 0, stream>>>(bsum, nb, rowptr, N);
    scan_p3<<<(unsigned)nb, 256, 0, stream>>>(deg, bsum, rowptr, cursor, N);
    scatter_bucketed<<<eg, 256, 0, stream>>>(src, dst, vals, cursor, bcur, brec, n2, h, NU, usel, filt);
    debucket<<<(unsigned)nbk, 256, 0, stream>>>(brec, rowptr, edata, N);
    if (!filt) {
      spmm_l1<<<(unsigned)((N + 3) / 4), 256, 0, stream>>>(rowptr, edata, usersF, itemF, ul1, il1, 0, N, NU);
    } else {
      spmm_l1<<<(unsigned)((NI + 3) / 4), 256, 0, stream>>>(rowptr, edata, usersF, itemF, ul1, il1, NU, NI, NU);
      spmm_l1_uid<<<(unsigned)((B + 3) / 4), 256, 0, stream>>>(rowptr, edata, itemF, ul1, uid, B);
    }
    if (itemOut)
      final_item<<<(unsigned)((NI + 3) / 4), 256, 0, stream>>>(rowptr, edata, ul1, il1, itemF, itemOut, NU, NI);
    final_uid<<<(unsigned)((B + 3) / 4), 256, 0, stream>>>(rowptr, edata, il1, ul1, usersF, uid, ug, add, B);
  };

  run_graph(uc_src, uc_dst, uc_vals, n2_uc, NC, coursesF, 0, c1, 0);
  run_graph(ue_src, ue_dst, ue_vals, n2_ue, NE, exF,      0, e1, 1);
  run_graph(uk_src, uk_dst, uk_vals, n2_uk, NK, knF,      1, nullptr, 1);

  attn_final<<<B, 64, 0, stream>>>(e1, pe, seq, mask, wq_w, wq_b, wk_w, wk_b,
                                   wv_w, wv_b, mlp_w, mlp_b, ug, c1, cid, (float*)d_out, T);
}

// Round 10
// 1469.347 us; speedup vs baseline: 3.7395x; 3.7395x over previous
//
#include <hip/hip_runtime.h>
#include <cmath>

#define D 64
#define BSHIFT 14            // bucket = 16384 CSR positions
#define BMASK 16383
#define PA_TILE 4096

__device__ __forceinline__ float wave_reduce_sum(float v) {
  #pragma unroll
  for (int off = 32; off > 0; off >>= 1) v += __shfl_xor(v, off, 64);
  return v;
}
__device__ __forceinline__ float wave_reduce_max(float v) {
  #pragma unroll
  for (int off = 32; off > 0; off >>= 1) v = fmaxf(v, __shfl_xor(v, off, 64));
  return v;
}
__device__ __forceinline__ int wave_reduce_sum_i(int v) {
  #pragma unroll
  for (int off = 32; off > 0; off >>= 1) v += __shfl_xor(v, off, 64);
  return v;
}

// ---- row accumulate: 4 edge-groups x 16 lanes, lane owns dims 4c..4c+3 ----
__device__ __forceinline__ void row_accum4(const int2* __restrict__ edata, int lo, int hi,
                                           const float* __restrict__ ftab, int g, int c4,
                                           float4& acc) {
  for (int base = lo; base < hi; base += 8) {
    int j0 = base + g, j1 = base + 4 + g;
    int2 e0 = (j0 < hi) ? edata[j0] : make_int2(0, 0);
    int2 e1 = (j1 < hi) ? edata[j1] : make_int2(0, 0);
    float4 f0 = *(const float4*)(ftab + (size_t)e0.x * D + c4);
    float4 f1 = *(const float4*)(ftab + (size_t)e1.x * D + c4);
    float v0 = __int_as_float(e0.y), v1 = __int_as_float(e1.y);
    acc.x = fmaf(v0, f0.x, acc.x); acc.y = fmaf(v0, f0.y, acc.y);
    acc.z = fmaf(v0, f0.z, acc.z); acc.w = fmaf(v0, f0.w, acc.w);
    acc.x = fmaf(v1, f1.x, acc.x); acc.y = fmaf(v1, f1.y, acc.y);
    acc.z = fmaf(v1, f1.z, acc.z); acc.w = fmaf(v1, f1.w, acc.w);
  }
}
// dual-table version (same index -> userF and ul1)
__device__ __forceinline__ void row_accum4x2(const int2* __restrict__ edata, int lo, int hi,
                                             const float* __restrict__ tab1,
                                             const float* __restrict__ tab2, int g, int c4,
                                             float4& a1, float4& a2) {
  for (int base = lo; base < hi; base += 4) {
    int j = base + g;
    int2 e = (j < hi) ? edata[j] : make_int2(0, 0);
    float v = __int_as_float(e.y);
    float4 f1 = *(const float4*)(tab1 + (size_t)e.x * D + c4);
    float4 f2 = *(const float4*)(tab2 + (size_t)e.x * D + c4);
    a1.x = fmaf(v, f1.x, a1.x); a1.y = fmaf(v, f1.y, a1.y);
    a1.z = fmaf(v, f1.z, a1.z); a1.w = fmaf(v, f1.w, a1.w);
    a2.x = fmaf(v, f2.x, a2.x); a2.y = fmaf(v, f2.y, a2.y);
    a2.z = fmaf(v, f2.z, a2.z); a2.w = fmaf(v, f2.w, a2.w);
  }
}

__device__ __forceinline__ float4 cg_reduce4(float4 a) {
  a.x += __shfl_xor(a.x, 16, 64); a.x += __shfl_xor(a.x, 32, 64);
  a.y += __shfl_xor(a.y, 16, 64); a.y += __shfl_xor(a.y, 32, 64);
  a.z += __shfl_xor(a.z, 16, 64); a.z += __shfl_xor(a.z, 32, 64);
  a.w += __shfl_xor(a.w, 16, 64); a.w += __shfl_xor(a.w, 32, 64);
  return a;
}

// ---------------- CSR build ----------------

__global__ void mark_usel(const int* __restrict__ uid, int* __restrict__ usel, int B) {
  int b = blockIdx.x * blockDim.x + threadIdx.x;
  if (b < B) usel[uid[b]] = 1;
}

// histogram + per-edge arrival slot (coalesced 2B write; deg max << 65536)
__global__ void relpos_k(const int* __restrict__ src, unsigned short* __restrict__ relpos,
                         int* __restrict__ deg, int n, int h,
                         const int* __restrict__ usel, int filt) {
  int e = blockIdx.x * blockDim.x + threadIdx.x;
  if (e >= n) return;
  int s = src[e];
  if (filt && e < h && usel[s] == 0) return;
  relpos[e] = (unsigned short)atomicAdd(&deg[s], 1);
}

// ---- coalesced 3-pass exclusive scan over deg[N] -> rowptr[N+1] ----
#define SCHUNK 2048

__global__ void scan_p1(const int* __restrict__ deg, int* __restrict__ bsum, int N) {
  int b = blockIdx.x, t = threadIdx.x;
  int lo = b * SCHUNK;
  int s = 0;
  #pragma unroll
  for (int k = 0; k < 8; ++k) { int i = lo + k * 256 + t; if (i < N) s += deg[i]; }
  s = wave_reduce_sum_i(s);
  __shared__ int ws[4];
  if ((t & 63) == 0) ws[t >> 6] = s;
  __syncthreads();
  if (t == 0) bsum[b] = ws[0] + ws[1] + ws[2] + ws[3];
}

__global__ __launch_bounds__(1024) void scan_p2(int* __restrict__ bsum, int nb,
                                                int* __restrict__ rowptr, int N) {
  __shared__ int arr[1024];
  int t = threadIdx.x;
  int v = (t < nb) ? bsum[t] : 0;
  arr[t] = v; __syncthreads();
  for (int off = 1; off < 1024; off <<= 1) {
    int x = (t >= off) ? arr[t - off] : 0;
    __syncthreads();
    arr[t] += x;
    __syncthreads();
  }
  if (t < nb) bsum[t] = t ? arr[t - 1] : 0;
  if (t == 0) rowptr[N] = arr[nb - 1];
}

__global__ void scan_p3(const int* __restrict__ deg, const int* __restrict__ bsum,
                        int* __restrict__ rowptr, int N) {
  int b = blockIdx.x, t = threadIdx.x;
  int lane = t & 63, wid = t >> 6;
  int base = b * SCHUNK + t * 8;
  int x[8], excl[8], s = 0;
  #pragma unroll
  for (int k = 0; k < 8; ++k) x[k] = (base + k < N) ? deg[base + k] : 0;
  #pragma unroll
  for (int k = 0; k < 8; ++k) { excl[k] = s; s += x[k]; }
  int incl = s;
  #pragma unroll
  for (int off = 1; off < 64; off <<= 1) {
    int y = __shfl_up(incl, off, 64);
    if (lane >= off) incl += y;
  }
  int wave_excl = incl - s;
  __shared__ int wsumS[4];
  if (lane == 63) wsumS[wid] = incl;
  __syncthreads();
  int wo = 0;
  for (int w = 0; w < wid; ++w) wo += wsumS[w];
  int off0 = bsum[b] + wo + wave_excl;
  #pragma unroll
  for (int k = 0; k < 8; ++k) {
    int i = base + k;
    if (i < N) rowptr[i] = off0 + excl[k];
  }
}

// ---- Pass A: block-local counting sort by bucket, grouped line-burst appends ----
// No cursor atomics: pos = rowptr[src] + relpos. Bucket fits a byte (255 = dropped).
__global__ __launch_bounds__(256) void scatter_grouped(
    const int* __restrict__ src, const int* __restrict__ dst,
    const float* __restrict__ vals, const unsigned short* __restrict__ relpos,
    const int* __restrict__ rowptr, int* __restrict__ bcur, uint2* __restrict__ brec,
    int n, int h, int NU, const int* __restrict__ usel, int filt, int nbkt) {
  __shared__ int lhist[256];
  __shared__ int lbase[256];
  __shared__ int gofs[256];
  __shared__ int lcur[256];
  __shared__ uint2 sorted[PA_TILE];
  __shared__ unsigned char sbkt[PA_TILE];
  int t = threadIdx.x;
  int base = blockIdx.x * PA_TILE;
  lhist[t] = 0;
  __syncthreads();

  int   mybkt[16];
  unsigned myrec[16], myval[16];
  #pragma unroll
  for (int k = 0; k < 16; ++k) {
    int e = base + k * 256 + t;
    int bkt = 255; unsigned rec = 0, vb = 0;
    if (e < n) {
      int s = src[e];
      bool keep = !(filt && e < h && usel[s] == 0);
      if (keep) {
        int tt = dst[e]; if (e < h) tt -= NU;      // local index on the other side
        int pos = rowptr[s] + (int)relpos[e];
        bkt = pos >> BSHIFT;
        rec = (unsigned)(pos & BMASK) | ((unsigned)tt << BSHIFT);
        vb  = __float_as_uint(vals[e]);
      }
    }
    mybkt[k] = bkt; myrec[k] = rec; myval[k] = vb;
    if (bkt != 255) atomicAdd(&lhist[bkt], 1);
  }
  __syncthreads();
  if (t == 0) {                       // small serial scan (nbkt <= 184)
    int run = 0;
    for (int i = 0; i < nbkt; ++i) { int c = lhist[i]; lbase[i] = run; run += c; }
    lbase[255] = run;                 // total kept in this tile
  }
  __syncthreads();
  if (t < nbkt) {
    int c = lhist[t];
    int g = (c > 0) ? atomicAdd(&bcur[t], c) : 0;
    gofs[t] = g - lbase[t];
    lcur[t] = lbase[t];
  }
  __syncthreads();
  #pragma unroll
  for (int k = 0; k < 16; ++k) {
    int bkt = mybkt[k];
    if (bkt != 255) {
      int slot = atomicAdd(&lcur[bkt], 1);
      sorted[slot] = make_uint2(myrec[k], myval[k]);
      sbkt[slot] = (unsigned char)bkt;
    }
  }
  __syncthreads();
  int total = lbase[255];
  for (int i = t; i < total; i += 256) {
    int bkt = sbkt[i];
    brec[((size_t)bkt << BSHIFT) + (size_t)(gofs[bkt] + i)] = sorted[i];
  }
}

// ---- Pass B: per-bucket LDS permute to exact CSR order; coalesced both ways ----
__global__ __launch_bounds__(256) void debucket(const uint2* __restrict__ brec,
                                                const int* __restrict__ rowptr,
                                                int2* __restrict__ edata, int N) {
  __shared__ int2 lds[1 << BSHIFT];   // 128 KiB (OK on gfx950: 160 KiB/CU)
  int b = blockIdx.x, t = threadIdx.x;
  int total = rowptr[N];
  int base = b << BSHIFT;
  int nb = total - base;
  if (nb <= 0) return;
  if (nb > (1 << BSHIFT)) nb = 1 << BSHIFT;
  for (int k = t; k < nb; k += 256) {
    uint2 r = brec[(size_t)base + k];
    lds[r.x & BMASK] = make_int2((int)(r.x >> BSHIFT), (int)r.y);
  }
  __syncthreads();
  for (int k = t; k < nb; k += 256) edata[(size_t)base + k] = lds[k];
}

// ---------------- SpMM layer kernels ----------------

// user rows [0,NU): ul1[u] = sum v*itemF[i]   (itemF small: L2-resident)
__global__ void spmm_user(const int* __restrict__ rowptr, const int2* __restrict__ edata,
                          const float* __restrict__ itemF, float* __restrict__ ul1, int NU) {
  int r = blockIdx.x * 4 + (threadIdx.x >> 6);
  if (r >= NU) return;
  int lane = threadIdx.x & 63, g = lane >> 4, c4 = (lane & 15) * 4;
  float4 a = make_float4(0.f, 0.f, 0.f, 0.f);
  row_accum4(edata, rowptr[r], rowptr[r + 1], itemF, g, c4, a);
  a = cg_reduce4(a);
  if (g == 0) *(float4*)(ul1 + (size_t)r * D + c4) = a;
}

// item rows, fused layer1+layer2: il1[i] = sum v*userF[u]; itemOut[i]=(itemF+il1+sum v*ul1[u])/3
__global__ void item_fused(const int* __restrict__ rowptr, const int2* __restrict__ edata,
                           const float* __restrict__ userF, const float* __restrict__ ul1,
                           const float* __restrict__ itemF, float* __restrict__ il1,
                           float* __restrict__ itemOut, int NU, int NI) {
  int i = blockIdx.x * 4 + (threadIdx.x >> 6);
  if (i >= NI) return;
  int lane = threadIdx.x & 63, g = lane >> 4, c4 = (lane & 15) * 4;
  int r = NU + i;
  float4 a1 = make_float4(0.f, 0.f, 0.f, 0.f);
  float4 a2 = a1;
  row_accum4x2(edata, rowptr[r], rowptr[r + 1], userF, ul1, g, c4, a1, a2);
  a1 = cg_reduce4(a1); a2 = cg_reduce4(a2);
  if (g == 0) {
    size_t o = (size_t)i * D + c4;
    *(float4*)(il1 + o) = a1;
    float4 itf = *(const float4*)(itemF + o);
    float4 res;
    res.x = (itf.x + a1.x + a2.x) * (1.f / 3.f);
    res.y = (itf.y + a1.y + a2.y) * (1.f / 3.f);
    res.z = (itf.z + a1.z + a2.z) * (1.f / 3.f);
    res.w = (itf.w + a1.w + a2.w) * (1.f / 3.f);
    *(float4*)(itemOut + o) = res;
  }
}

// item rows, layer1 only (uk): il1[i] = sum v*userF[u]
__global__ void spmm_item(const int* __restrict__ rowptr, const int2* __restrict__ edata,
                          const float* __restrict__ userF, float* __restrict__ il1,
                          int NU, int NI) {
  int i = blockIdx.x * 4 + (threadIdx.x >> 6);
  if (i >= NI) return;
  int lane = threadIdx.x & 63, g = lane >> 4, c4 = (lane & 15) * 4;
  int r = NU + i;
  float4 a = make_float4(0.f, 0.f, 0.f, 0.f);
  row_accum4(edata, rowptr[r], rowptr[r + 1], userF, g, c4, a);
  a = cg_reduce4(a);
  if (g == 0) *(float4*)(il1 + (size_t)i * D + c4) = a;
}

// layer1 at batch user rows only (uk): ul1[uid[b]] = sum v*itemF
__global__ void spmm_l1_uid(const int* __restrict__ rowptr, const int2* __restrict__ edata,
                            const float* __restrict__ itemF, float* __restrict__ ul1,
                            const int* __restrict__ uid, int B) {
  int b = blockIdx.x * 4 + (threadIdx.x >> 6);
  if (b >= B) return;
  int lane = threadIdx.x & 63, g = lane >> 4, c4 = (lane & 15) * 4;
  int r = uid[b];
  float4 a = make_float4(0.f, 0.f, 0.f, 0.f);
  row_accum4(edata, rowptr[r], rowptr[r + 1], itemF, g, c4, a);
  a = cg_reduce4(a);
  if (g == 0) *(float4*)(ul1 + (size_t)r * D + c4) = a;
}

// layer2+avg at batch users: ug[b] (+)= (userF[u] + ul1[u] + sum v*il1[dst]) / 3
__global__ void final_uid(const int* __restrict__ rowptr, const int2* __restrict__ edata,
                          const float* __restrict__ il1, const float* __restrict__ ul1,
                          const float* __restrict__ userF, const int* __restrict__ uid,
                          float* __restrict__ ug, int add, int B) {
  int b = blockIdx.x * 4 + (threadIdx.x >> 6);
  if (b >= B) return;
  int lane = threadIdx.x & 63, g = lane >> 4, c4 = (lane & 15) * 4;
  int u = uid[b];
  float4 a = make_float4(0.f, 0.f, 0.f, 0.f);
  row_accum4(edata, rowptr[u], rowptr[u + 1], il1, g, c4, a);
  a = cg_reduce4(a);
  if (g == 0) {
    size_t uo = (size_t)u * D + c4;
    float4 uf = *(const float4*)(userF + uo);
    float4 ul = *(const float4*)(ul1 + uo);
    float4 res;
    res.x = (uf.x + ul.x + a.x) * (1.f / 3.f);
    res.y = (uf.y + ul.y + a.y) * (1.f / 3.f);
    res.z = (uf.z + ul.z + a.z) * (1.f / 3.f);
    res.w = (uf.w + ul.w + a.w) * (1.f / 3.f);
    float4* dstp = (float4*)(ug + (size_t)b * D + c4);
    if (add) {
      float4 old = *dstp;
      res.x += old.x; res.y += old.y; res.z += old.z; res.w += old.w;
    }
    *dstp = res;
  }
}

// ---------------- fused attention + MLP + output ----------------

__global__ __launch_bounds__(64) void attn_final(
    const float* __restrict__ e1, const float* __restrict__ pe,
    const int* __restrict__ seq, const int* __restrict__ mask,
    const float* __restrict__ wq_w, const float* __restrict__ wq_b,
    const float* __restrict__ wk_w, const float* __restrict__ wk_b,
    const float* __restrict__ wv_w, const float* __restrict__ wv_b,
    const float* __restrict__ mlp_w, const float* __restrict__ mlp_b,
    const float* __restrict__ ug, const float* __restrict__ c1,
    const int* __restrict__ cid, float* __restrict__ out, int T) {
  __shared__ float xs[64][D];
  __shared__ float wks[D * D];
  __shared__ float wvs[D * D];
  __shared__ float ps[D];
  __shared__ float ys[D];
  __shared__ float atts[D];
  int b = blockIdx.x, d = threadIdx.x;

  for (int i = d; i < D * D; i += 64) { wks[i] = wk_w[i]; wvs[i] = wv_w[i]; }
  for (int t = 0; t < T; ++t) {
    int sidx = seq[b * T + t];
    xs[t][d] = e1[(size_t)sidx * D + d] + pe[t * D + d];
  }
  __syncthreads();

  float qd = wq_b[d];
  #pragma unroll 4
  for (int j = 0; j < D; ++j) qd = fmaf(xs[T - 1][j], wq_w[j * D + d], qd);
  if (mask[b * T + (T - 1)] == 0) qd = -100000.0f;

  float my_score = -INFINITY;
  for (int t = 0; t < T; ++t) {
    float kd = wk_b[d];
    #pragma unroll 8
    for (int j = 0; j < D; ++j) kd = fmaf(xs[t][j], wks[j * D + d], kd);
    if (mask[b * T + t] == 0) kd = -100000.0f;
    float s = wave_reduce_sum(qd * kd) * 0.125f;
    if (d == t) my_score = s;
  }
  float m = wave_reduce_max(my_score);
  float p = (d < T) ? expf(my_score - m) : 0.f;
  float sum = wave_reduce_sum(p);
  ps[d] = p / sum;
  __syncthreads();

  float yj = 0.f;
  for (int t = 0; t < T; ++t) yj = fmaf(ps[t], xs[t][d], yj);
  ys[d] = yj;
  __syncthreads();
  float ad = wv_b[d];
  #pragma unroll 8
  for (int j = 0; j < D; ++j) ad = fmaf(ys[j], wvs[j * D + d], ad);
  atts[d] = ad;
  __syncthreads();

  float h = mlp_b[d];
  #pragma unroll 4
  for (int j = 0; j < D; ++j) h = fmaf(ug[(size_t)b * D + j], mlp_w[j * D + d], h);
  #pragma unroll 4
  for (int j = 0; j < D; ++j) h = fmaf(atts[j], mlp_w[(D + j) * D + d], h);
  h = fmaxf(h, 0.f);

  #pragma unroll
  for (int c = 0; c < 2; ++c) {
    int cc = cid[b * 2 + c];
    float s = wave_reduce_sum(h * c1[(size_t)cc * D + d]);
    if (d == 0) out[b * 2 + c] = s;
  }
}

// ---------------- host ----------------

extern "C" void kernel_launch(void* const* d_in, const int* in_sizes, int n_in,
                              void* d_out, int out_size, void* d_ws, size_t ws_size,
                              hipStream_t stream) {
  const float* usersF   = (const float*)d_in[0];
  const float* coursesF = (const float*)d_in[1];
  const float* exF      = (const float*)d_in[2];
  const float* knF      = (const float*)d_in[3];
  const float* wq_w = (const float*)d_in[4];
  const float* wq_b = (const float*)d_in[5];
  const float* wk_w = (const float*)d_in[6];
  const float* wk_b = (const float*)d_in[7];
  const float* wv_w = (const float*)d_in[8];
  const float* wv_b = (const float*)d_in[9];
  const float* mlp_w = (const float*)d_in[10];
  const float* mlp_b = (const float*)d_in[11];
  const float* pe = (const float*)d_in[12];
  const float* uc_vals = (const float*)d_in[13];
  const float* ue_vals = (const float*)d_in[14];
  const float* uk_vals = (const float*)d_in[15];
  const int* uc_src = (const int*)d_in[16];
  const int* uc_dst = (const int*)d_in[17];
  const int* ue_src = (const int*)d_in[18];
  const int* ue_dst = (const int*)d_in[19];
  const int* uk_src = (const int*)d_in[20];
  const int* uk_dst = (const int*)d_in[21];
  const int* mask = (const int*)d_in[22];
  const int* seq  = (const int*)d_in[23];
  const int* uid  = (const int*)d_in[24];
  const int* cid  = (const int*)d_in[25];

  int NU = in_sizes[0] / D;
  int NC = in_sizes[1] / D;
  int NE = in_sizes[2] / D;
  int NK = in_sizes[3] / D;
  int B  = in_sizes[24];
  int T  = in_sizes[22] / B;
  int n2_uc = in_sizes[13], n2_ue = in_sizes[14], n2_uk = in_sizes[15];

  int NImax = NC > NE ? NC : NE; NImax = NImax > NK ? NImax : NK;
  int Nmax = NU + NImax;
  int n2max = n2_uc > n2_ue ? n2_uc : n2_ue; n2max = n2max > n2_uk ? n2max : n2_uk;
  int nbkmax = (n2max + BMASK) >> BSHIFT;

  char* w = (char*)d_ws;
  auto alloc = [&](size_t bytes) { void* p = (void*)w; w += (bytes + 255) & ~(size_t)255; return p; };
  int2*  edata  = (int2*)alloc((size_t)n2max * 8);
  float* ul1    = (float*)alloc((size_t)NU * D * 4);   // brec overlays this during build
  float* il1    = (float*)alloc((size_t)NImax * D * 4);
  float* e1     = (float*)alloc((size_t)NE * D * 4);
  float* c1     = (float*)alloc((size_t)NC * D * 4);
  float* ug     = (float*)alloc((size_t)B * D * 4);
  int*   rowptr = (int*)alloc((size_t)(Nmax + 1) * 4);
  int*   deg    = (int*)alloc((size_t)Nmax * 4);
  unsigned short* relpos = (unsigned short*)alloc((size_t)n2max * 2);
  int*   usel   = (int*)alloc((size_t)NU * 4);
  int*   bsum   = (int*)alloc((size_t)1024 * 4);
  int*   bcur   = (int*)alloc((size_t)(nbkmax + 1) * 4);
  uint2* brec   = (uint2*)ul1;   // dead outside [passA, passB]; ul1 rewritten after

  hipMemsetAsync(usel, 0, (size_t)NU * 4, stream);
  mark_usel<<<(B + 255) / 256, 256, 0, stream>>>(uid, usel, B);

  auto run_graph = [&](const int* src, const int* dst, const float* vals, int n2,
                       int NI, const float* itemF, int filt, float* itemOut, int add) {
    int N = NU + NI;
    int h = n2 / 2;
    unsigned eg = (unsigned)((n2 + 255) / 256);
    int nb = (N + SCHUNK - 1) / SCHUNK;
    int nbk = (n2 + BMASK) >> BSHIFT;
    hipMemsetAsync(deg, 0, (size_t)N * 4, stream);
    hipMemsetAsync(bcur, 0, (size_t)nbk * 4, stream);
    relpos_k<<<eg, 256, 0, stream>>>(src, relpos, deg, n2, h, usel, filt);
    scan_p1<<<(unsigned)nb, 256, 0, stream>>>(deg, bsum, N);
    scan_p2<<<1, 1024, 0, stream>>>(bsum, nb, rowptr, N);
    scan_p3<<<(unsigned)nb, 256, 0, stream>>>(deg, bsum, rowptr, N);
    scatter_grouped<<<(unsigned)((n2 + PA_TILE - 1) / PA_TILE), 256, 0, stream>>>(
        src, dst, vals, relpos, rowptr, bcur, brec, n2, h, NU, usel, filt, nbk);
    debucket<<<(unsigned)nbk, 256, 0, stream>>>(brec, rowptr, edata, N);
    if (!filt) {
      spmm_user<<<(unsigned)((NU + 3) / 4), 256, 0, stream>>>(rowptr, edata, itemF, ul1, NU);
      item_fused<<<(unsigned)((NI + 3) / 4), 256, 0, stream>>>(rowptr, edata, usersF, ul1,
                                                               itemF, il1, itemOut, NU, NI);
    } else {
      spmm_item<<<(unsigned)((NI + 3) / 4), 256, 0, stream>>>(rowptr, edata, usersF, il1, NU, NI);
      spmm_l1_uid<<<(unsigned)((B + 3) / 4), 256, 0, stream>>>(rowptr, edata, itemF, ul1, uid, B);
    }
    final_uid<<<(unsigned)((B + 3) / 4), 256, 0, stream>>>(rowptr, edata, il1, ul1, usersF, uid, ug, add, B);
  };

  run_graph(uc_src, uc_dst, uc_vals, n2_uc, NC, coursesF, 0, c1, 0);
  run_graph(ue_src, ue_dst, ue_vals, n2_ue, NE, exF,      0, e1, 1);
  run_graph(uk_src, uk_dst, uk_vals, n2_uk, NK, knF,      1, nullptr, 1);

  attn_final<<<B, 64, 0, stream>>>(e1, pe, seq, mask, wq_w, wq_b, wk_w, wk_b,
                                   wv_w, wv_b, mlp_w, mlp_b, ug, c1, cid, (float*)d_out, T);
}